// Round 10
// baseline (2304.504 us; speedup 1.0000x reference)
//
#include <hip/hip_runtime.h>
#include <hip/hip_bf16.h>
#include <math.h>

#define SEQ 1024
#define HID 512
#define FOURH 2048
#define IND 400
#define NT 13

#define LSTM_WGS 64        // blocks 0..63: LSTM role (32/dir)
#define NGEMM 256          // blocks 64..319: pre-GEMM role
#define JPW 16             // hidden units per LSTM WG
#define WCOLS 64           // gate columns per LSTM WG
#define TAG_INVALID 0xFFFFFFFFu

__device__ __forceinline__ float bf2f(unsigned short u) {
    union { unsigned u32; float f; } v;
    v.u32 = ((unsigned)u) << 16;
    return v.f;
}

__device__ __forceinline__ unsigned short f2bf(float f) {
    union { float f; unsigned u; } v;
    v.f = f;
    unsigned u = v.u;
    unsigned rounding = 0x7FFFu + ((u >> 16) & 1u);
    u += rounding;
    return (unsigned short)(u >> 16);
}

__device__ __forceinline__ float ldf(const void* p, size_t i, int isf32) {
    return isf32 ? ((const float*)p)[i] : bf2f(((const unsigned short*)p)[i]);
}

__device__ __forceinline__ float fsigm(float x) {
    return __builtin_amdgcn_rcpf(1.f + __builtin_amdgcn_exp2f(-1.44269504f * x));
}
__device__ __forceinline__ float ftanhf(float x) {
    return 1.f - 2.f * __builtin_amdgcn_rcpf(__builtin_amdgcn_exp2f(2.88539008f * x) + 1.f);
}
__device__ __forceinline__ float satz(float z) { return fminf(fmaxf(z, -60.f), 60.f); }

// ---------------------------------------------------------------- dtype detect + counter/flag zero
__global__ __launch_bounds__(64) void detect_kernel(const unsigned short* __restrict__ w,
                                                    int* __restrict__ flag,
                                                    unsigned* __restrict__ vcnt,
                                                    unsigned* __restrict__ flags) {
    int lane = threadIdx.x;
    int cnt = 0;
    for (int i = 0; i < 4; ++i) {
        unsigned short u = w[2 * (lane * 4 + i)];   // low half if buffer is f32
        int e = (u >> 7) & 0xFF;
        if (e >= 90 && e < 127) cnt++;
    }
#pragma unroll
    for (int off = 32; off >= 1; off >>= 1) cnt += __shfl_xor(cnt, off, 64);
    if (lane == 0) *flag = (cnt < 128) ? 1 : 0;    // 1 => inputs are float32
    if (lane == 1) *vcnt = 0;                      // outproj->viterbi completion counter
    flags[lane] = 0;                               // 64 pre-row-block ready flags [dir][by]
}

// ---------------------------------------------------------------- FUSED pre-GEMM + persistent LSTM
// Grid = 320 blocks x 512 thr. Blocks 64..319 compute pre = feat @ Wx + b (one
// (dir,bx,by) tile each: 512 cols x 32 rows), write it as packed-u64 AGENT-scope
// atomic stores (4 bf16/word -> LLC, cross-XCD visible), drain vmcnt, then
// atomicAdd flags[dir][by]. by-order is front/back interleaved so by=0 (fwd
// start) and by=31 (bwd start) finish first. GEMM blocks never wait on anything
// -> they always complete -> flags always set (no deadlock mode). All 320
// blocks are co-resident (52KB LDS -> 3 blocks/CU cap; 16 waves/CU max).
// Blocks 0..63 run the R9-verified LSTM (dual-copy tagged h-exchange, 64-lane
// epilogue) unchanged except: pre is read via agent-scope u64 atomic loads,
// gated per row-block crossing on flags (monotonic, cached after first pass).
// This recovers pre_gemm's serial slot: it now runs on the 192 idle CUs.
__global__ __launch_bounds__(512, 2) void fused_kernel(
        const int* __restrict__ x, const int* __restrict__ cas, const int* __restrict__ pos,
        const void* __restrict__ W_emb, const void* __restrict__ W_cas, const void* __restrict__ W_pos,
        const void* __restrict__ Wx_f, const void* __restrict__ b_f,
        const void* __restrict__ Wx_b, const void* __restrict__ b_b,
        const void* __restrict__ Wh_f, const void* __restrict__ Wh_b,
        const void* __restrict__ h0, const void* __restrict__ c0,
        unsigned long long* __restrict__ preu, float* __restrict__ hsout,
        unsigned long long* hbuf, const int* __restrict__ dflag,
        unsigned* __restrict__ flags) {
    __shared__ float smem[12800 + 96];   // gemm: ftile+idxs (51.6KB); lstm: red[2][512] (4KB)
    const int isf32 = *dflag;
    const int tid = threadIdx.x;
    const int b = blockIdx.x;

    if (b >= LSTM_WGS) {
        // ================= GEMM role =================
        const int e = b - LSTM_WGS;          // 0..255
        const int gdir = e & 1;
        const int rest = e >> 1;
        const int bx = rest & 3;             // col-block of 512
        const int byi = rest >> 2;           // 0..31 priority index
        const int by = (byi & 1) ? (31 - (byi >> 1)) : (byi >> 1);
        const void* Wx = gdir ? Wx_b : Wx_f;
        const void* bb = gdir ? b_b : b_f;
        const int r0 = by * 32;
        const int col = bx * 512 + tid;
        float* ftile = smem;
        int* idxs = (int*)&smem[12800];

        if (tid < 32)       idxs[tid] = x[r0 + tid];
        else if (tid < 64)  idxs[tid] = cas[r0 + tid - 32];
        else if (tid < 96)  idxs[tid] = pos[r0 + tid - 64];
        __syncthreads();

        for (int idx = tid; idx < 32 * IND; idx += 512) {
            int r = idx / IND;
            int el = idx - r * IND;
            float v;
            if (el < 300)      v = ldf(W_emb, (size_t)idxs[r] * 300 + el, isf32);
            else if (el < 350) v = ldf(W_cas, (size_t)idxs[32 + r] * 50 + (el - 300), isf32);
            else               v = ldf(W_pos, (size_t)idxs[64 + r] * 50 + (el - 350), isf32);
            ftile[idx] = v;
        }
        __syncthreads();

        float acc[32];
        float bias = ldf(bb, col, isf32);
#pragma unroll
        for (int r = 0; r < 32; ++r) acc[r] = bias;

        if (isf32) {
            const float* W = (const float*)Wx;
            for (int kk = 0; kk < 100; ++kk) {
                int k = kk * 4;
                float w0 = W[(size_t)(k + 0) * FOURH + col];
                float w1 = W[(size_t)(k + 1) * FOURH + col];
                float w2 = W[(size_t)(k + 2) * FOURH + col];
                float w3 = W[(size_t)(k + 3) * FOURH + col];
#pragma unroll
                for (int r = 0; r < 32; ++r) {
                    float4 f = *(const float4*)&ftile[r * IND + k];
                    acc[r] += f.x * w0 + f.y * w1 + f.z * w2 + f.w * w3;
                }
            }
        } else {
            const unsigned short* W = (const unsigned short*)Wx;
            for (int kk = 0; kk < 100; ++kk) {
                int k = kk * 4;
                float w0 = bf2f(W[(size_t)(k + 0) * FOURH + col]);
                float w1 = bf2f(W[(size_t)(k + 1) * FOURH + col]);
                float w2 = bf2f(W[(size_t)(k + 2) * FOURH + col]);
                float w3 = bf2f(W[(size_t)(k + 3) * FOURH + col]);
#pragma unroll
                for (int r = 0; r < 32; ++r) {
                    float4 f = *(const float4*)&ftile[r * IND + k];
                    acc[r] += f.x * w0 + f.y * w1 + f.z * w2 + f.w * w3;
                }
            }
        }

        // pack 4 cols -> u64, agent-scope atomic store (cross-XCD visible at LLC)
        unsigned long long* dst = preu + (size_t)gdir * SEQ * (FOURH / 4);
        for (int r = 0; r < 32; ++r) {
            unsigned long long w = ((unsigned long long)f2bf(acc[r])) << (16 * (tid & 3));
            w |= __shfl_xor(w, 1, 64);
            w |= __shfl_xor(w, 2, 64);
            if ((tid & 3) == 0)
                __hip_atomic_store(&dst[(size_t)(r0 + r) * 512 + (col >> 2)], w,
                                   __ATOMIC_RELAXED, __HIP_MEMORY_SCOPE_AGENT);
        }
        asm volatile("s_waitcnt vmcnt(0)" ::: "memory");   // my stores at LLC
        __syncthreads();                                    // whole block drained
        if (tid == 0) atomicAdd(&flags[gdir * 32 + by], 1u);  // 4 => row-block ready
        return;
    }

    // ================= LSTM role (R9-verified) =================
    float* redp = smem;                      // red[2][512]
    const int dir = b & 1;
    const int g = b >> 1;                    // 0..31
    const int j0 = g * JPW;

    const void* Wh = dir ? Wh_b : Wh_f;
    const unsigned long long* preu_d = preu + (size_t)dir * SEQ * 512;
    float* hso = hsout + (size_t)dir * SEQ * HID;
    unsigned long long* hb_d  = hbuf + dir * 2 * HID;          // copy A
    unsigned long long* hb2_d = hbuf + 4096 + dir * 2 * HID;   // copy B (+32 KB)

    const int seg  = tid >> 6;
    const int col  = tid & 63;
    const int unit = col & 15;
    const int gate = col >> 4;
    const int gcol = gate * HID + j0 + unit;
    const int redoff = seg * WCOLS + unit * 4 + gate;

    const int isep  = (tid < 64);
    const int eunit = tid >> 2;              // 0..15
    const int egate = tid & 3;               // 0..3
    const int ispub = isep && (egate == 0);
    const int sub   = eunit & 3;             // bf16 slot within the u64
    const int widx  = egate * 128 + ((j0 + eunit) >> 2);   // u64 index within a row

    // ---- stage Wh into 16 NAMED float4 registers ----
    float4 w0, w1, w2, w3, w4, w5, w6, w7, w8, w9, w10, w11, w12, w13, w14, w15;
    if (isf32) {
        const float* wp = (const float*)Wh + (size_t)(seg * 64) * FOURH + gcol;
#define LDW(i) w##i = make_float4(wp[(size_t)(4*i+0)*FOURH], wp[(size_t)(4*i+1)*FOURH], \
                                  wp[(size_t)(4*i+2)*FOURH], wp[(size_t)(4*i+3)*FOURH])
        LDW(0); LDW(1); LDW(2); LDW(3); LDW(4); LDW(5); LDW(6); LDW(7);
        LDW(8); LDW(9); LDW(10); LDW(11); LDW(12); LDW(13); LDW(14); LDW(15);
#undef LDW
    } else {
        const unsigned short* wp = (const unsigned short*)Wh + (size_t)(seg * 64) * FOURH + gcol;
#define LDW(i) w##i = make_float4(bf2f(wp[(size_t)(4*i+0)*FOURH]), bf2f(wp[(size_t)(4*i+1)*FOURH]), \
                                  bf2f(wp[(size_t)(4*i+2)*FOURH]), bf2f(wp[(size_t)(4*i+3)*FOURH]))
        LDW(0); LDW(1); LDW(2); LDW(3); LDW(4); LDW(5); LDW(6); LDW(7);
        LDW(8); LDW(9); LDW(10); LDW(11); LDW(12); LDW(13); LDW(14); LDW(15);
#undef LDW
    }

    float creg = 0.f;
    unsigned long long znw = 0;              // prefetched pre u64 (4 bf16)
    int curby = dir ? 31 : 0;
    if (isep) {
        if (ispub) {
            creg = ldf(c0, dir * HID + j0 + eunit, isf32);
            float h0v = ldf(h0, dir * HID + j0 + eunit, isf32);
            unsigned long long wv = (unsigned long long)__float_as_uint(h0v);
            unsigned long long iv = ((unsigned long long)TAG_INVALID << 32);
            __hip_atomic_store(&hb_d[j0 + eunit],        wv, __ATOMIC_RELAXED, __HIP_MEMORY_SCOPE_AGENT);
            __hip_atomic_store(&hb2_d[j0 + eunit],       wv, __ATOMIC_RELAXED, __HIP_MEMORY_SCOPE_AGENT);
            __hip_atomic_store(&hb_d[HID + j0 + eunit],  iv, __ATOMIC_RELAXED, __HIP_MEMORY_SCOPE_AGENT);
            __hip_atomic_store(&hb2_d[HID + j0 + eunit], iv, __ATOMIC_RELAXED, __HIP_MEMORY_SCOPE_AGENT);
        }
        // wait for the first pre row-block, then prefetch row t0
        {
            const unsigned* fp = &flags[dir * 32 + curby];
            while (__hip_atomic_load(fp, __ATOMIC_RELAXED, __HIP_MEMORY_SCOPE_AGENT) < 4u) {}
        }
        int t0 = dir ? (SEQ - 1) : 0;
        znw = __hip_atomic_load(&preu_d[(size_t)t0 * 512 + widx],
                                __ATOMIC_RELAXED, __HIP_MEMORY_SCOPE_AGENT);
    }
    __syncthreads();   // drains vmcnt: h-inits on their way before anyone spins

    for (int s = 0; s < SEQ; ++s) {
        const int t = dir ? (SEQ - 1 - s) : s;

        // ---- alternating dual-address poll on own tagged word (lane owns k=tid) ----
        unsigned hu;
        {
            const unsigned long long* A = &hb_d[(s & 1) * HID + tid];
            const unsigned long long* B = &hb2_d[(s & 1) * HID + tid];
            const unsigned expect = (unsigned)s;
            unsigned long long va = __hip_atomic_load(A, __ATOMIC_RELAXED, __HIP_MEMORY_SCOPE_AGENT);
            unsigned long long vb = __hip_atomic_load(B, __ATOMIC_RELAXED, __HIP_MEMORY_SCOPE_AGENT);
            for (;;) {
                if ((unsigned)(va >> 32) == expect) { hu = (unsigned)va; break; }
                va = __hip_atomic_load(A, __ATOMIC_RELAXED, __HIP_MEMORY_SCOPE_AGENT);
                if ((unsigned)(vb >> 32) == expect) { hu = (unsigned)vb; break; }
                vb = __hip_atomic_load(B, __ATOMIC_RELAXED, __HIP_MEMORY_SCOPE_AGENT);
            }
        }

        // epilogue lanes: consume prefetched pre, gate on row-block flag, prefetch next
        float zc = 0.f;
        if (isep) {
            zc = bf2f((unsigned short)(znw >> (16 * sub)));
            if (s + 1 < SEQ) {
                int tn = dir ? (SEQ - 2 - s) : (s + 1);
                int byn = tn >> 5;
                if (byn != curby) {
                    const unsigned* fp = &flags[dir * 32 + byn];
                    while (__hip_atomic_load(fp, __ATOMIC_RELAXED, __HIP_MEMORY_SCOPE_AGENT) < 4u) {}
                    curby = byn;
                }
                znw = __hip_atomic_load(&preu_d[(size_t)tn * 512 + widx],
                                        __ATOMIC_RELAXED, __HIP_MEMORY_SCOPE_AGENT);
            }
        }

        // ---- matvec: h broadcast via readlane (no LDS, no barrier) ----
        float a0 = 0.f, a1 = 0.f, a2 = 0.f, a3 = 0.f;
#define MACQ(i, A) { \
        float hx = __uint_as_float((unsigned)__builtin_amdgcn_readlane((int)hu, 4*i+0)); \
        float hy = __uint_as_float((unsigned)__builtin_amdgcn_readlane((int)hu, 4*i+1)); \
        float hz = __uint_as_float((unsigned)__builtin_amdgcn_readlane((int)hu, 4*i+2)); \
        float hw = __uint_as_float((unsigned)__builtin_amdgcn_readlane((int)hu, 4*i+3)); \
        A += hx * w##i.x + hy * w##i.y + hz * w##i.z + hw * w##i.w; }
        MACQ(0, a0)  MACQ(1, a1)  MACQ(2, a2)  MACQ(3, a3)
        MACQ(4, a0)  MACQ(5, a1)  MACQ(6, a2)  MACQ(7, a3)
        MACQ(8, a0)  MACQ(9, a1)  MACQ(10, a2) MACQ(11, a3)
        MACQ(12, a0) MACQ(13, a1) MACQ(14, a2) MACQ(15, a3)
#undef MACQ
        redp[(s & 1) * 512 + redoff] = (a0 + a1) + (a2 + a3);
        __syncthreads();   // the ONE barrier: all 8 waves' red(s) complete

        // ---- 64-lane epilogue + dual publish ----
        if (isep) {
            const float* rp = &redp[(s & 1) * 512];
            float z = rp[0 * WCOLS + tid] + rp[1 * WCOLS + tid]
                    + rp[2 * WCOLS + tid] + rp[3 * WCOLS + tid]
                    + rp[4 * WCOLS + tid] + rp[5 * WCOLS + tid]
                    + rp[6 * WCOLS + tid] + rp[7 * WCOLS + tid];
            z = satz(z + zc);
            float vs = fsigm(z);
            float vt = ftanhf(z);
            float v = (egate == 2) ? vt : vs;     // i,f,o: sigmoid; g: tanh
            float x1 = __shfl_xor(v, 1, 64);
            float x2 = __shfl_xor(v, 2, 64);
            float x3 = __shfl_xor(x1, 2, 64);
            if (ispub) {
                float ig = v, fg = x1, gg = x2, og = x3;
                float cnew = fg * creg + ig * gg;
                creg = cnew;
                float hnew = og * ftanhf(satz(cnew));
                unsigned long long w = ((unsigned long long)(unsigned)(s + 1) << 32)
                                     | (unsigned long long)__float_as_uint(hnew);
                const int par = (s + 1) & 1;
                __hip_atomic_store(&hb_d[par * HID + j0 + eunit], w,
                                   __ATOMIC_RELAXED, __HIP_MEMORY_SCOPE_AGENT);
                __hip_atomic_store(&hb2_d[par * HID + j0 + eunit], w,
                                   __ATOMIC_RELAXED, __HIP_MEMORY_SCOPE_AGENT);
                hso[(size_t)t * HID + j0 + eunit] = hnew;
            }
        }
        // no trailing barrier: next iteration's tag-spin + red parity is the sync
    }
}

// ---------------------------------------------------------------- outproj + log_softmax + (last block) viterbi
__global__ __launch_bounds__(64) void outproj_kernel(const float* __restrict__ hsout,
        const void* __restrict__ W_out, const void* __restrict__ b_out,
        float* __restrict__ out_scores,
        const void* __restrict__ trans, const void* __restrict__ strans,
        const void* __restrict__ etrans, float* __restrict__ out_path,
        unsigned* __restrict__ vcnt, const int* __restrict__ dflag) {
    __shared__ unsigned char hist[SEQ][NT];
    const int isf32 = *dflag;
    int t = blockIdx.x;
    int lane = threadIdx.x;
    const float* hf = hsout + (size_t)t * HID;
    const float* hb = hsout + (size_t)SEQ * HID + (size_t)t * HID;
    float acc[NT];
#pragma unroll
    for (int j = 0; j < NT; ++j) acc[j] = 0.f;
    for (int k = lane; k < HID; k += 64) {
        float a = hf[k], b2 = hb[k];
#pragma unroll
        for (int j = 0; j < NT; ++j)
            acc[j] += a * ldf(W_out, (size_t)k * NT + j, isf32)
                    + b2 * ldf(W_out, (size_t)(HID + k) * NT + j, isf32);
    }
#pragma unroll
    for (int off = 32; off >= 1; off >>= 1) {
#pragma unroll
        for (int j = 0; j < NT; ++j) acc[j] += __shfl_xor(acc[j], off, 64);
    }
    float o[NT];
    float m = -1e30f;
#pragma unroll
    for (int j = 0; j < NT; ++j) { o[j] = acc[j] + ldf(b_out, j, isf32); m = fmaxf(m, o[j]); }
    float lse = 0.f;
#pragma unroll
    for (int j = 0; j < NT; ++j) lse += expf(o[j] - m);
    lse = m + logf(lse);
    if (lane < NT)
        __hip_atomic_store(&out_scores[t * NT + lane], o[lane] - lse,
                           __ATOMIC_RELAXED, __HIP_MEMORY_SCOPE_AGENT);
    __builtin_amdgcn_s_waitcnt(0);   // stores ack'd at LLC before the arrival add

    unsigned old = 0;
    if (lane == 0) old = atomicAdd(vcnt, 1u);
    old = __shfl(old, 0, 64);
    if (old != SEQ - 1) return;

    const float* em = out_scores;
    int j = lane < NT ? lane : 0;
    float tr[NT];
#pragma unroll
    for (int i = 0; i < NT; ++i) tr[i] = ldf(trans, i * NT + j, isf32);
#define EML(tt) __hip_atomic_load(&em[(size_t)(tt) * NT + j], __ATOMIC_RELAXED, __HIP_MEMORY_SCOPE_AGENT)
    float score = ldf(strans, j, isf32) + EML(0);
    float c0 = EML(1), c1 = EML(2), c2 = EML(3), c3 = EML(4),
          c4 = EML(5), c5 = EML(6), c6 = EML(7), c7 = EML(8);
#define VSTEP(PE, TT) { \
    float best = -1e30f; int arg = 0; \
    _Pragma("unroll") \
    for (int i = 0; i < NT; ++i) { \
        float si = __shfl(score, i, 64); \
        float cand = si + tr[i]; \
        if (cand > best) { best = cand; arg = i; } \
    } \
    if (lane < NT) hist[TT][lane] = (unsigned char)arg; \
    score = best + PE; }
    for (int tb = 1; tb < SEQ; tb += 8) {
        int nb = tb + 8;
        float n0 = 0.f, n1 = 0.f, n2 = 0.f, n3 = 0.f, n4 = 0.f, n5 = 0.f, n6 = 0.f, n7 = 0.f;
        if (nb + 0 < SEQ) n0 = EML(nb + 0);
        if (nb + 1 < SEQ) n1 = EML(nb + 1);
        if (nb + 2 < SEQ) n2 = EML(nb + 2);
        if (nb + 3 < SEQ) n3 = EML(nb + 3);
        if (nb + 4 < SEQ) n4 = EML(nb + 4);
        if (nb + 5 < SEQ) n5 = EML(nb + 5);
        if (nb + 6 < SEQ) n6 = EML(nb + 6);
        if (nb + 7 < SEQ) n7 = EML(nb + 7);
        VSTEP(c0, tb + 0)
        if (tb + 1 < SEQ) VSTEP(c1, tb + 1)
        if (tb + 2 < SEQ) VSTEP(c2, tb + 2)
        if (tb + 3 < SEQ) VSTEP(c3, tb + 3)
        if (tb + 4 < SEQ) VSTEP(c4, tb + 4)
        if (tb + 5 < SEQ) VSTEP(c5, tb + 5)
        if (tb + 6 < SEQ) VSTEP(c6, tb + 6)
        if (tb + 7 < SEQ) VSTEP(c7, tb + 7)
        c0 = n0; c1 = n1; c2 = n2; c3 = n3; c4 = n4; c5 = n5; c6 = n6; c7 = n7;
    }
#undef VSTEP
#undef EML
    score += ldf(etrans, j, isf32);
    float bmax = -1e30f;
    int last = 0;
#pragma unroll
    for (int i = 0; i < NT; ++i) {
        float si = __shfl(score, i, 64);
        if (si > bmax) { bmax = si; last = i; }
    }
    if (lane == 0) {
        int cur = last;
        out_path[SEQ - 1] = (float)cur;
        for (int tt = SEQ - 1; tt >= 1; --tt) {
            cur = hist[tt][cur];
            out_path[tt - 1] = (float)cur;
        }
    }
}

// ---------------------------------------------------------------- launch
extern "C" void kernel_launch(void* const* d_in, const int* in_sizes, int n_in,
                              void* d_out, int out_size, void* d_ws, size_t ws_size,
                              hipStream_t stream) {
    const int* x      = (const int*)d_in[0];
    const int* casing = (const int*)d_in[1];
    const int* posi   = (const int*)d_in[2];
    const void* h0    = d_in[3];
    const void* c0    = d_in[4];
    const void* W_emb = d_in[5];
    const void* W_cas = d_in[6];
    const void* W_pos = d_in[7];
    const void* Wx_f  = d_in[8];
    const void* Wh_f  = d_in[9];
    const void* b_f   = d_in[10];
    const void* Wx_b  = d_in[11];
    const void* Wh_b  = d_in[12];
    const void* b_b   = d_in[13];
    const void* W_out = d_in[14];
    const void* b_out = d_in[15];
    const void* trans = d_in[16];
    const void* strans = d_in[17];
    const void* etrans = d_in[18];

    // workspace layout (~12.7 MB)
    char* ws = (char*)d_ws;
    int* dflag          = (int*)(ws + 448);
    unsigned* vcnt      = (unsigned*)(ws + 456);
    unsigned long long* preu = (unsigned long long*)(ws + 512);   // 2*1024*512 u64 = 8,388,608 B
    float* hsout        = (float*)(ws + 512 + 8388608);           // 4,194,304 B
    // h exchange: copy A at +0, copy B at +32KB (64KB window)
    unsigned long long* hbuf = (unsigned long long*)(ws + 512 + 8388608 + 4194304);
    unsigned* flags     = (unsigned*)(ws + 512 + 8388608 + 4194304 + 65536);  // [2][32]

    float* out_scores = (float*)d_out;
    float* out_path   = out_scores + SEQ * NT;

    detect_kernel<<<1, 64, 0, stream>>>((const unsigned short*)W_emb, dflag, vcnt, flags);

    fused_kernel<<<LSTM_WGS + NGEMM, 512, 0, stream>>>(
        x, casing, posi, W_emb, W_cas, W_pos, Wx_f, b_f, Wx_b, b_b,
        Wh_f, Wh_b, h0, c0, preu, hsout, hbuf, dflag, flags);

    outproj_kernel<<<SEQ, 64, 0, stream>>>(hsout, W_out, b_out, out_scores,
                                           trans, strans, etrans, out_path, vcnt, dflag);
}

// Round 11
// 2260.500 us; speedup vs baseline: 1.0195x; 1.0195x over previous
//
#include <hip/hip_runtime.h>
#include <hip/hip_bf16.h>
#include <math.h>

#define SEQ 1024
#define HID 512
#define FOURH 2048
#define IND 400
#define NT 13

#define LSTM_WGS 64        // blocks 0..63: LSTM role (32/dir)
#define NGEMM 192          // blocks 64..255: pre-GEMM role (grid=256 -> no cross-role CU sharing)
#define JPW 16             // hidden units per LSTM WG
#define WCOLS 64           // gate columns per LSTM WG
#define TAG_INVALID 0xFFFFFFFFu

__device__ __forceinline__ float bf2f(unsigned short u) {
    union { unsigned u32; float f; } v;
    v.u32 = ((unsigned)u) << 16;
    return v.f;
}

__device__ __forceinline__ unsigned short f2bf(float f) {
    union { float f; unsigned u; } v;
    v.f = f;
    unsigned u = v.u;
    unsigned rounding = 0x7FFFu + ((u >> 16) & 1u);
    u += rounding;
    return (unsigned short)(u >> 16);
}

__device__ __forceinline__ float ldf(const void* p, size_t i, int isf32) {
    return isf32 ? ((const float*)p)[i] : bf2f(((const unsigned short*)p)[i]);
}

__device__ __forceinline__ float fsigm(float x) {
    return __builtin_amdgcn_rcpf(1.f + __builtin_amdgcn_exp2f(-1.44269504f * x));
}
__device__ __forceinline__ float ftanhf(float x) {
    return 1.f - 2.f * __builtin_amdgcn_rcpf(__builtin_amdgcn_exp2f(2.88539008f * x) + 1.f);
}
__device__ __forceinline__ float satz(float z) { return fminf(fmaxf(z, -60.f), 60.f); }

// ---------------------------------------------------------------- dtype detect + counter/flag zero
__global__ __launch_bounds__(64) void detect_kernel(const unsigned short* __restrict__ w,
                                                    int* __restrict__ flag,
                                                    unsigned* __restrict__ vcnt,
                                                    unsigned* __restrict__ flags) {
    int lane = threadIdx.x;
    int cnt = 0;
    for (int i = 0; i < 4; ++i) {
        unsigned short u = w[2 * (lane * 4 + i)];   // low half if buffer is f32
        int e = (u >> 7) & 0xFF;
        if (e >= 90 && e < 127) cnt++;
    }
#pragma unroll
    for (int off = 32; off >= 1; off >>= 1) cnt += __shfl_xor(cnt, off, 64);
    if (lane == 0) *flag = (cnt < 128) ? 1 : 0;    // 1 => inputs are float32
    if (lane == 1) *vcnt = 0;                      // outproj->viterbi completion counter
    flags[lane] = 0;                               // 64 pre-row-block ready flags [dir][by]
}

// ---------------------------------------------------------------- FUSED pre-GEMM + persistent LSTM
// Grid = 256 blocks x 512 thr (<=2 blocks/CU, role-contiguous IDs -> lstm never
// shares a CU with gemm). Blocks 64..255 compute pre = feat @ Wx + b and write
// it as packed-u64 AGENT-scope atomic stores (cross-XCD visible at LLC), drain
// vmcnt, then atomicAdd flags[dir][by]. Startup-critical row-blocks (fwd by=0,
// bwd by=31) are split 8-ways (256-col tiles, flag threshold 8) -> ~4x faster
// ready. Remaining 31 by x 4 bx = 124 tiles/dir run on 88 blocks/dir; 36 do a
// second tile assigned to row-blocks the lstm reaches ~1000us later (slack 7x).
// GEMM blocks never wait -> always complete -> flags always set (no deadlock).
// Blocks 0..63 run the R9-verified LSTM (dual-copy tagged h-exchange, 64-lane
// epilogue); pre is read via agent-scope u64 atomic loads gated per row-block
// crossing on flags (threshold 8 for the critical block, 4 otherwise).
__global__ __launch_bounds__(512, 2) void fused_kernel(
        const int* __restrict__ x, const int* __restrict__ cas, const int* __restrict__ pos,
        const void* __restrict__ W_emb, const void* __restrict__ W_cas, const void* __restrict__ W_pos,
        const void* __restrict__ Wx_f, const void* __restrict__ b_f,
        const void* __restrict__ Wx_b, const void* __restrict__ b_b,
        const void* __restrict__ Wh_f, const void* __restrict__ Wh_b,
        const void* __restrict__ h0, const void* __restrict__ c0,
        unsigned long long* __restrict__ preu, float* __restrict__ hsout,
        unsigned long long* hbuf, const int* __restrict__ dflag,
        unsigned* __restrict__ flags) {
    __shared__ float smem[12800 + 96];   // gemm: ftile+idxs (51.6KB); lstm: red[2][512] (4KB)
    const int isf32 = *dflag;
    const int tid = threadIdx.x;
    const int b = blockIdx.x;

    if (b >= LSTM_WGS) {
        // ================= GEMM role =================
        const int e = b - LSTM_WGS;          // 0..191
        const int gdir = e & 1;
        const int i = e >> 1;                // 0..95
        const void* Wx = gdir ? Wx_b : Wx_f;
        const void* bb = gdir ? b_b : b_f;
        unsigned long long* dst = preu + (size_t)gdir * SEQ * 512;
        float* ftile = smem;
        int* idxs = (int*)&smem[12800];
        const int critby = gdir ? 31 : 0;

        if (i < 8) {
            // ---- critical tile: 256 cols x 32 rows of row-block critby ----
            const int r0 = critby * 32;
            const int c  = tid & 255;
            const int rg = tid >> 8;          // 0..1, 16 rows each
            const int col = i * 256 + c;      // 0..2047

            if (tid < 32)       idxs[tid] = x[r0 + tid];
            else if (tid < 64)  idxs[tid] = cas[r0 + tid - 32];
            else if (tid < 96)  idxs[tid] = pos[r0 + tid - 64];
            __syncthreads();
            for (int idx = tid; idx < 32 * IND; idx += 512) {
                int r = idx / IND;
                int el = idx - r * IND;
                float v;
                if (el < 300)      v = ldf(W_emb, (size_t)idxs[r] * 300 + el, isf32);
                else if (el < 350) v = ldf(W_cas, (size_t)idxs[32 + r] * 50 + (el - 300), isf32);
                else               v = ldf(W_pos, (size_t)idxs[64 + r] * 50 + (el - 350), isf32);
                ftile[idx] = v;
            }
            __syncthreads();

            float acc[16];
            float bias = ldf(bb, col, isf32);
#pragma unroll
            for (int r = 0; r < 16; ++r) acc[r] = bias;

            if (isf32) {
                const float* W = (const float*)Wx;
                for (int kk = 0; kk < 100; ++kk) {
                    int k = kk * 4;
                    float w0 = W[(size_t)(k + 0) * FOURH + col];
                    float w1 = W[(size_t)(k + 1) * FOURH + col];
                    float w2 = W[(size_t)(k + 2) * FOURH + col];
                    float w3 = W[(size_t)(k + 3) * FOURH + col];
#pragma unroll
                    for (int rr = 0; rr < 16; ++rr) {
                        float4 f = *(const float4*)&ftile[(rg * 16 + rr) * IND + k];
                        acc[rr] += f.x * w0 + f.y * w1 + f.z * w2 + f.w * w3;
                    }
                }
            } else {
                const unsigned short* W = (const unsigned short*)Wx;
                for (int kk = 0; kk < 100; ++kk) {
                    int k = kk * 4;
                    float w0 = bf2f(W[(size_t)(k + 0) * FOURH + col]);
                    float w1 = bf2f(W[(size_t)(k + 1) * FOURH + col]);
                    float w2 = bf2f(W[(size_t)(k + 2) * FOURH + col]);
                    float w3 = bf2f(W[(size_t)(k + 3) * FOURH + col]);
#pragma unroll
                    for (int rr = 0; rr < 16; ++rr) {
                        float4 f = *(const float4*)&ftile[(rg * 16 + rr) * IND + k];
                        acc[rr] += f.x * w0 + f.y * w1 + f.z * w2 + f.w * w3;
                    }
                }
            }

            for (int rr = 0; rr < 16; ++rr) {
                int r = rg * 16 + rr;
                unsigned long long w = ((unsigned long long)f2bf(acc[rr])) << (16 * (tid & 3));
                w |= __shfl_xor(w, 1, 64);
                w |= __shfl_xor(w, 2, 64);
                if ((tid & 3) == 0)
                    __hip_atomic_store(&dst[(size_t)(r0 + r) * 512 + (col >> 2)], w,
                                       __ATOMIC_RELAXED, __HIP_MEMORY_SCOPE_AGENT);
            }
            asm volatile("s_waitcnt vmcnt(0)" ::: "memory");
            __syncthreads();
            if (tid == 0) atomicAdd(&flags[gdir * 32 + critby], 1u);   // 8 => ready
            return;
        }

        // ---- standard tiles: 512 cols x 32 rows; 1 or 2 per block ----
        const int j = i - 8;                 // 0..87
        const int q = j >> 2;                // 0..21
        const int ntile = (j < 36) ? 2 : 1;
        for (int ti = 0; ti < ntile; ++ti) {
            const int by = (ti == 0) ? (gdir ? (30 - q) : (1 + q))
                                     : (gdir ? (8 - q)  : (23 + q));
            const int bx = j & 3;
            const int r0 = by * 32;
            const int col = bx * 512 + tid;

            __syncthreads();                 // safe smem reuse across iterations
            if (tid < 32)       idxs[tid] = x[r0 + tid];
            else if (tid < 64)  idxs[tid] = cas[r0 + tid - 32];
            else if (tid < 96)  idxs[tid] = pos[r0 + tid - 64];
            __syncthreads();
            for (int idx = tid; idx < 32 * IND; idx += 512) {
                int r = idx / IND;
                int el = idx - r * IND;
                float v;
                if (el < 300)      v = ldf(W_emb, (size_t)idxs[r] * 300 + el, isf32);
                else if (el < 350) v = ldf(W_cas, (size_t)idxs[32 + r] * 50 + (el - 300), isf32);
                else               v = ldf(W_pos, (size_t)idxs[64 + r] * 50 + (el - 350), isf32);
                ftile[idx] = v;
            }
            __syncthreads();

            float acc[32];
            float bias = ldf(bb, col, isf32);
#pragma unroll
            for (int r = 0; r < 32; ++r) acc[r] = bias;

            if (isf32) {
                const float* W = (const float*)Wx;
                for (int kk = 0; kk < 100; ++kk) {
                    int k = kk * 4;
                    float w0 = W[(size_t)(k + 0) * FOURH + col];
                    float w1 = W[(size_t)(k + 1) * FOURH + col];
                    float w2 = W[(size_t)(k + 2) * FOURH + col];
                    float w3 = W[(size_t)(k + 3) * FOURH + col];
#pragma unroll
                    for (int r = 0; r < 32; ++r) {
                        float4 f = *(const float4*)&ftile[r * IND + k];
                        acc[r] += f.x * w0 + f.y * w1 + f.z * w2 + f.w * w3;
                    }
                }
            } else {
                const unsigned short* W = (const unsigned short*)Wx;
                for (int kk = 0; kk < 100; ++kk) {
                    int k = kk * 4;
                    float w0 = bf2f(W[(size_t)(k + 0) * FOURH + col]);
                    float w1 = bf2f(W[(size_t)(k + 1) * FOURH + col]);
                    float w2 = bf2f(W[(size_t)(k + 2) * FOURH + col]);
                    float w3 = bf2f(W[(size_t)(k + 3) * FOURH + col]);
#pragma unroll
                    for (int r = 0; r < 32; ++r) {
                        float4 f = *(const float4*)&ftile[r * IND + k];
                        acc[r] += f.x * w0 + f.y * w1 + f.z * w2 + f.w * w3;
                    }
                }
            }

            for (int r = 0; r < 32; ++r) {
                unsigned long long w = ((unsigned long long)f2bf(acc[r])) << (16 * (tid & 3));
                w |= __shfl_xor(w, 1, 64);
                w |= __shfl_xor(w, 2, 64);
                if ((tid & 3) == 0)
                    __hip_atomic_store(&dst[(size_t)(r0 + r) * 512 + (col >> 2)], w,
                                       __ATOMIC_RELAXED, __HIP_MEMORY_SCOPE_AGENT);
            }
            asm volatile("s_waitcnt vmcnt(0)" ::: "memory");
            __syncthreads();
            if (tid == 0) atomicAdd(&flags[gdir * 32 + by], 1u);       // 4 => ready
        }
        return;
    }

    // ================= LSTM role (R9-verified) =================
    float* redp = smem;                      // red[2][512]
    const int dir = b & 1;
    const int g = b >> 1;                    // 0..31
    const int j0 = g * JPW;
    const int critby = dir ? 31 : 0;

    const void* Wh = dir ? Wh_b : Wh_f;
    const unsigned long long* preu_d = preu + (size_t)dir * SEQ * 512;
    float* hso = hsout + (size_t)dir * SEQ * HID;
    unsigned long long* hb_d  = hbuf + dir * 2 * HID;          // copy A
    unsigned long long* hb2_d = hbuf + 4096 + dir * 2 * HID;   // copy B (+32 KB)

    const int seg  = tid >> 6;
    const int col  = tid & 63;
    const int unit = col & 15;
    const int gate = col >> 4;
    const int gcol = gate * HID + j0 + unit;
    const int redoff = seg * WCOLS + unit * 4 + gate;

    const int isep  = (tid < 64);
    const int eunit = tid >> 2;              // 0..15
    const int egate = tid & 3;               // 0..3
    const int ispub = isep && (egate == 0);
    const int sub   = eunit & 3;             // bf16 slot within the u64
    const int widx  = egate * 128 + ((j0 + eunit) >> 2);   // u64 index within a row

    // ---- stage Wh into 16 NAMED float4 registers ----
    float4 w0, w1, w2, w3, w4, w5, w6, w7, w8, w9, w10, w11, w12, w13, w14, w15;
    if (isf32) {
        const float* wp = (const float*)Wh + (size_t)(seg * 64) * FOURH + gcol;
#define LDW(i) w##i = make_float4(wp[(size_t)(4*i+0)*FOURH], wp[(size_t)(4*i+1)*FOURH], \
                                  wp[(size_t)(4*i+2)*FOURH], wp[(size_t)(4*i+3)*FOURH])
        LDW(0); LDW(1); LDW(2); LDW(3); LDW(4); LDW(5); LDW(6); LDW(7);
        LDW(8); LDW(9); LDW(10); LDW(11); LDW(12); LDW(13); LDW(14); LDW(15);
#undef LDW
    } else {
        const unsigned short* wp = (const unsigned short*)Wh + (size_t)(seg * 64) * FOURH + gcol;
#define LDW(i) w##i = make_float4(bf2f(wp[(size_t)(4*i+0)*FOURH]), bf2f(wp[(size_t)(4*i+1)*FOURH]), \
                                  bf2f(wp[(size_t)(4*i+2)*FOURH]), bf2f(wp[(size_t)(4*i+3)*FOURH]))
        LDW(0); LDW(1); LDW(2); LDW(3); LDW(4); LDW(5); LDW(6); LDW(7);
        LDW(8); LDW(9); LDW(10); LDW(11); LDW(12); LDW(13); LDW(14); LDW(15);
#undef LDW
    }

    float creg = 0.f;
    unsigned long long znw = 0;              // prefetched pre u64 (4 bf16)
    int curby = critby;
    if (isep) {
        if (ispub) {
            creg = ldf(c0, dir * HID + j0 + eunit, isf32);
            float h0v = ldf(h0, dir * HID + j0 + eunit, isf32);
            unsigned long long wv = (unsigned long long)__float_as_uint(h0v);
            unsigned long long iv = ((unsigned long long)TAG_INVALID << 32);
            __hip_atomic_store(&hb_d[j0 + eunit],        wv, __ATOMIC_RELAXED, __HIP_MEMORY_SCOPE_AGENT);
            __hip_atomic_store(&hb2_d[j0 + eunit],       wv, __ATOMIC_RELAXED, __HIP_MEMORY_SCOPE_AGENT);
            __hip_atomic_store(&hb_d[HID + j0 + eunit],  iv, __ATOMIC_RELAXED, __HIP_MEMORY_SCOPE_AGENT);
            __hip_atomic_store(&hb2_d[HID + j0 + eunit], iv, __ATOMIC_RELAXED, __HIP_MEMORY_SCOPE_AGENT);
        }
        // wait for the critical pre row-block (threshold 8), prefetch row t0
        {
            const unsigned* fp = &flags[dir * 32 + curby];
            while (__hip_atomic_load(fp, __ATOMIC_RELAXED, __HIP_MEMORY_SCOPE_AGENT) < 8u) {}
        }
        int t0 = dir ? (SEQ - 1) : 0;
        znw = __hip_atomic_load(&preu_d[(size_t)t0 * 512 + widx],
                                __ATOMIC_RELAXED, __HIP_MEMORY_SCOPE_AGENT);
    }
    __syncthreads();   // drains vmcnt: h-inits on their way before anyone spins

    for (int s = 0; s < SEQ; ++s) {
        const int t = dir ? (SEQ - 1 - s) : s;

        // ---- alternating dual-address poll on own tagged word (lane owns k=tid) ----
        unsigned hu;
        {
            const unsigned long long* A = &hb_d[(s & 1) * HID + tid];
            const unsigned long long* B = &hb2_d[(s & 1) * HID + tid];
            const unsigned expect = (unsigned)s;
            unsigned long long va = __hip_atomic_load(A, __ATOMIC_RELAXED, __HIP_MEMORY_SCOPE_AGENT);
            unsigned long long vb = __hip_atomic_load(B, __ATOMIC_RELAXED, __HIP_MEMORY_SCOPE_AGENT);
            for (;;) {
                if ((unsigned)(va >> 32) == expect) { hu = (unsigned)va; break; }
                va = __hip_atomic_load(A, __ATOMIC_RELAXED, __HIP_MEMORY_SCOPE_AGENT);
                if ((unsigned)(vb >> 32) == expect) { hu = (unsigned)vb; break; }
                vb = __hip_atomic_load(B, __ATOMIC_RELAXED, __HIP_MEMORY_SCOPE_AGENT);
            }
        }

        // epilogue lanes: consume prefetched pre, gate on row-block flag, prefetch next
        float zc = 0.f;
        if (isep) {
            zc = bf2f((unsigned short)(znw >> (16 * sub)));
            if (s + 1 < SEQ) {
                int tn = dir ? (SEQ - 2 - s) : (s + 1);
                int byn = tn >> 5;
                if (byn != curby) {
                    const unsigned thr = (byn == critby) ? 8u : 4u;
                    const unsigned* fp = &flags[dir * 32 + byn];
                    while (__hip_atomic_load(fp, __ATOMIC_RELAXED, __HIP_MEMORY_SCOPE_AGENT) < thr) {}
                    curby = byn;
                }
                znw = __hip_atomic_load(&preu_d[(size_t)tn * 512 + widx],
                                        __ATOMIC_RELAXED, __HIP_MEMORY_SCOPE_AGENT);
            }
        }

        // ---- matvec: h broadcast via readlane (no LDS, no barrier) ----
        float a0 = 0.f, a1 = 0.f, a2 = 0.f, a3 = 0.f;
#define MACQ(i, A) { \
        float hx = __uint_as_float((unsigned)__builtin_amdgcn_readlane((int)hu, 4*i+0)); \
        float hy = __uint_as_float((unsigned)__builtin_amdgcn_readlane((int)hu, 4*i+1)); \
        float hz = __uint_as_float((unsigned)__builtin_amdgcn_readlane((int)hu, 4*i+2)); \
        float hw = __uint_as_float((unsigned)__builtin_amdgcn_readlane((int)hu, 4*i+3)); \
        A += hx * w##i.x + hy * w##i.y + hz * w##i.z + hw * w##i.w; }
        MACQ(0, a0)  MACQ(1, a1)  MACQ(2, a2)  MACQ(3, a3)
        MACQ(4, a0)  MACQ(5, a1)  MACQ(6, a2)  MACQ(7, a3)
        MACQ(8, a0)  MACQ(9, a1)  MACQ(10, a2) MACQ(11, a3)
        MACQ(12, a0) MACQ(13, a1) MACQ(14, a2) MACQ(15, a3)
#undef MACQ
        redp[(s & 1) * 512 + redoff] = (a0 + a1) + (a2 + a3);
        __syncthreads();   // the ONE barrier: all 8 waves' red(s) complete

        // ---- 64-lane epilogue + dual publish ----
        if (isep) {
            const float* rp = &redp[(s & 1) * 512];
            float z = rp[0 * WCOLS + tid] + rp[1 * WCOLS + tid]
                    + rp[2 * WCOLS + tid] + rp[3 * WCOLS + tid]
                    + rp[4 * WCOLS + tid] + rp[5 * WCOLS + tid]
                    + rp[6 * WCOLS + tid] + rp[7 * WCOLS + tid];
            z = satz(z + zc);
            float vs = fsigm(z);
            float vt = ftanhf(z);
            float v = (egate == 2) ? vt : vs;     // i,f,o: sigmoid; g: tanh
            float x1 = __shfl_xor(v, 1, 64);
            float x2 = __shfl_xor(v, 2, 64);
            float x3 = __shfl_xor(x1, 2, 64);
            if (ispub) {
                float ig = v, fg = x1, gg = x2, og = x3;
                float cnew = fg * creg + ig * gg;
                creg = cnew;
                float hnew = og * ftanhf(satz(cnew));
                unsigned long long w = ((unsigned long long)(unsigned)(s + 1) << 32)
                                     | (unsigned long long)__float_as_uint(hnew);
                const int par = (s + 1) & 1;
                __hip_atomic_store(&hb_d[par * HID + j0 + eunit], w,
                                   __ATOMIC_RELAXED, __HIP_MEMORY_SCOPE_AGENT);
                __hip_atomic_store(&hb2_d[par * HID + j0 + eunit], w,
                                   __ATOMIC_RELAXED, __HIP_MEMORY_SCOPE_AGENT);
                hso[(size_t)t * HID + j0 + eunit] = hnew;
            }
        }
        // no trailing barrier: next iteration's tag-spin + red parity is the sync
    }
}

// ---------------------------------------------------------------- outproj + log_softmax + (last block) viterbi
__global__ __launch_bounds__(64) void outproj_kernel(const float* __restrict__ hsout,
        const void* __restrict__ W_out, const void* __restrict__ b_out,
        float* __restrict__ out_scores,
        const void* __restrict__ trans, const void* __restrict__ strans,
        const void* __restrict__ etrans, float* __restrict__ out_path,
        unsigned* __restrict__ vcnt, const int* __restrict__ dflag) {
    __shared__ unsigned char hist[SEQ][NT];
    const int isf32 = *dflag;
    int t = blockIdx.x;
    int lane = threadIdx.x;
    const float* hf = hsout + (size_t)t * HID;
    const float* hb = hsout + (size_t)SEQ * HID + (size_t)t * HID;
    float acc[NT];
#pragma unroll
    for (int j = 0; j < NT; ++j) acc[j] = 0.f;
    for (int k = lane; k < HID; k += 64) {
        float a = hf[k], b2 = hb[k];
#pragma unroll
        for (int j = 0; j < NT; ++j)
            acc[j] += a * ldf(W_out, (size_t)k * NT + j, isf32)
                    + b2 * ldf(W_out, (size_t)(HID + k) * NT + j, isf32);
    }
#pragma unroll
    for (int off = 32; off >= 1; off >>= 1) {
#pragma unroll
        for (int j = 0; j < NT; ++j) acc[j] += __shfl_xor(acc[j], off, 64);
    }
    float o[NT];
    float m = -1e30f;
#pragma unroll
    for (int j = 0; j < NT; ++j) { o[j] = acc[j] + ldf(b_out, j, isf32); m = fmaxf(m, o[j]); }
    float lse = 0.f;
#pragma unroll
    for (int j = 0; j < NT; ++j) lse += expf(o[j] - m);
    lse = m + logf(lse);
    if (lane < NT)
        __hip_atomic_store(&out_scores[t * NT + lane], o[lane] - lse,
                           __ATOMIC_RELAXED, __HIP_MEMORY_SCOPE_AGENT);
    __builtin_amdgcn_s_waitcnt(0);   // stores ack'd at LLC before the arrival add

    unsigned old = 0;
    if (lane == 0) old = atomicAdd(vcnt, 1u);
    old = __shfl(old, 0, 64);
    if (old != SEQ - 1) return;

    const float* em = out_scores;
    int j = lane < NT ? lane : 0;
    float tr[NT];
#pragma unroll
    for (int i = 0; i < NT; ++i) tr[i] = ldf(trans, i * NT + j, isf32);
#define EML(tt) __hip_atomic_load(&em[(size_t)(tt) * NT + j], __ATOMIC_RELAXED, __HIP_MEMORY_SCOPE_AGENT)
    float score = ldf(strans, j, isf32) + EML(0);
    float c0 = EML(1), c1 = EML(2), c2 = EML(3), c3 = EML(4),
          c4 = EML(5), c5 = EML(6), c6 = EML(7), c7 = EML(8);
#define VSTEP(PE, TT) { \
    float best = -1e30f; int arg = 0; \
    _Pragma("unroll") \
    for (int i = 0; i < NT; ++i) { \
        float si = __shfl(score, i, 64); \
        float cand = si + tr[i]; \
        if (cand > best) { best = cand; arg = i; } \
    } \
    if (lane < NT) hist[TT][lane] = (unsigned char)arg; \
    score = best + PE; }
    for (int tb = 1; tb < SEQ; tb += 8) {
        int nb = tb + 8;
        float n0 = 0.f, n1 = 0.f, n2 = 0.f, n3 = 0.f, n4 = 0.f, n5 = 0.f, n6 = 0.f, n7 = 0.f;
        if (nb + 0 < SEQ) n0 = EML(nb + 0);
        if (nb + 1 < SEQ) n1 = EML(nb + 1);
        if (nb + 2 < SEQ) n2 = EML(nb + 2);
        if (nb + 3 < SEQ) n3 = EML(nb + 3);
        if (nb + 4 < SEQ) n4 = EML(nb + 4);
        if (nb + 5 < SEQ) n5 = EML(nb + 5);
        if (nb + 6 < SEQ) n6 = EML(nb + 6);
        if (nb + 7 < SEQ) n7 = EML(nb + 7);
        VSTEP(c0, tb + 0)
        if (tb + 1 < SEQ) VSTEP(c1, tb + 1)
        if (tb + 2 < SEQ) VSTEP(c2, tb + 2)
        if (tb + 3 < SEQ) VSTEP(c3, tb + 3)
        if (tb + 4 < SEQ) VSTEP(c4, tb + 4)
        if (tb + 5 < SEQ) VSTEP(c5, tb + 5)
        if (tb + 6 < SEQ) VSTEP(c6, tb + 6)
        if (tb + 7 < SEQ) VSTEP(c7, tb + 7)
        c0 = n0; c1 = n1; c2 = n2; c3 = n3; c4 = n4; c5 = n5; c6 = n6; c7 = n7;
    }
#undef VSTEP
#undef EML
    score += ldf(etrans, j, isf32);
    float bmax = -1e30f;
    int last = 0;
#pragma unroll
    for (int i = 0; i < NT; ++i) {
        float si = __shfl(score, i, 64);
        if (si > bmax) { bmax = si; last = i; }
    }
    if (lane == 0) {
        int cur = last;
        out_path[SEQ - 1] = (float)cur;
        for (int tt = SEQ - 1; tt >= 1; --tt) {
            cur = hist[tt][cur];
            out_path[tt - 1] = (float)cur;
        }
    }
}

// ---------------------------------------------------------------- launch
extern "C" void kernel_launch(void* const* d_in, const int* in_sizes, int n_in,
                              void* d_out, int out_size, void* d_ws, size_t ws_size,
                              hipStream_t stream) {
    const int* x      = (const int*)d_in[0];
    const int* casing = (const int*)d_in[1];
    const int* posi   = (const int*)d_in[2];
    const void* h0    = d_in[3];
    const void* c0    = d_in[4];
    const void* W_emb = d_in[5];
    const void* W_cas = d_in[6];
    const void* W_pos = d_in[7];
    const void* Wx_f  = d_in[8];
    const void* Wh_f  = d_in[9];
    const void* b_f   = d_in[10];
    const void* Wx_b  = d_in[11];
    const void* Wh_b  = d_in[12];
    const void* b_b   = d_in[13];
    const void* W_out = d_in[14];
    const void* b_out = d_in[15];
    const void* trans = d_in[16];
    const void* strans = d_in[17];
    const void* etrans = d_in[18];

    // workspace layout (~12.7 MB)
    char* ws = (char*)d_ws;
    int* dflag          = (int*)(ws + 448);
    unsigned* vcnt      = (unsigned*)(ws + 456);
    unsigned long long* preu = (unsigned long long*)(ws + 512);   // 2*1024*512 u64 = 8,388,608 B
    float* hsout        = (float*)(ws + 512 + 8388608);           // 4,194,304 B
    // h exchange: copy A at +0, copy B at +32KB (64KB window)
    unsigned long long* hbuf = (unsigned long long*)(ws + 512 + 8388608 + 4194304);
    unsigned* flags     = (unsigned*)(ws + 512 + 8388608 + 4194304 + 65536);  // [2][32]

    float* out_scores = (float*)d_out;
    float* out_path   = out_scores + SEQ * NT;

    detect_kernel<<<1, 64, 0, stream>>>((const unsigned short*)W_emb, dflag, vcnt, flags);

    fused_kernel<<<LSTM_WGS + NGEMM, 512, 0, stream>>>(
        x, casing, posi, W_emb, W_cas, W_pos, Wx_f, b_f, Wx_b, b_b,
        Wh_f, Wh_b, h0, c0, preu, hsout, hbuf, dflag, flags);

    outproj_kernel<<<SEQ, 64, 0, stream>>>(hsout, W_out, b_out, out_scores,
                                           trans, strans, etrans, out_path, vcnt, dflag);
}